// Round 2
// baseline (128.323 us; speedup 1.0000x reference)
//
#include <hip/hip_runtime.h>
#include <hip/hip_bf16.h>

// NT-Xent loss, N=4096, D=256, fp32 in, fp32 scalar out.
// loss = mean_i [ log( sum_{j != i} exp(2*cos_ij) ) - 2*cos_{i,pair(i)} ]
//
// R2: symmetric-triangle Gram (pair tiles I<=J over 64 groups of 128 rows),
// exp scale folded into A (znA = 2*log2e * zhat, znB = zhat so MFMA output is
// the exp2 exponent directly), 3 kernels total, pair term from bf16 (error
// ~5e-3 << 0.18 threshold).
//
// k1 normalize: z -> znA, znB; zero rowsum and d_out
// k2 gram: per pair-tile (I,J): S = znA_I . znB_J^T, v=exp2(S);
//          row-sums -> rowsum[I-rows]; col-sums (LDS-accumulated) -> rowsum[J-rows] (I<J only)
// k3 finalize: per pair (q, q+4096): lse = ln(rowsum - exp2(diag)) ; contrib -> atomicAdd d_out

#define NROWS 8192
#define NHALF 4096
#define DDIM  256
#define GT    128                       // rows per group
#define NTILES (NROWS / GT)             // 64
#define NBLK  (NTILES * (NTILES + 1) / 2)  // 2080
#define BN    64                        // staged cols per iter
#define LDSB  528                       // 512 + 16 pad per staged row

typedef __bf16 bf16;
typedef __bf16 bf16x4 __attribute__((ext_vector_type(4)));
typedef __bf16 bf16x8 __attribute__((ext_vector_type(8)));
typedef float  f32x4  __attribute__((ext_vector_type(4)));

__constant__ const float kC   = 2.8853900817779268f;  // 2*log2(e)
__constant__ const float kLn2 = 0.6931471805599453f;

// ---------------- k1: normalize ----------------
__global__ void k_normalize(const float* __restrict__ z1, const float* __restrict__ z2,
                            bf16* __restrict__ znA, bf16* __restrict__ znB,
                            float* __restrict__ rowsum, float* __restrict__ out) {
  const int wave = threadIdx.x >> 6, lane = threadIdx.x & 63;
  const int row = blockIdx.x * 4 + wave;
  const float* src = (row < NHALF) ? z1 + (size_t)row * DDIM
                                   : z2 + (size_t)(row - NHALF) * DDIM;
  f32x4 v = *(const f32x4*)(src + lane * 4);
  float ss = v.x * v.x + v.y * v.y + v.z * v.z + v.w * v.w;
#pragma unroll
  for (int off = 1; off < 64; off <<= 1) ss += __shfl_xor(ss, off);
  const float inv  = 1.0f / fmaxf(sqrtf(ss), 1e-8f);
  const float invc = inv * kC;
  bf16x4 oa, ob;
  oa.x = (bf16)(v.x * invc); oa.y = (bf16)(v.y * invc);
  oa.z = (bf16)(v.z * invc); oa.w = (bf16)(v.w * invc);
  ob.x = (bf16)(v.x * inv);  ob.y = (bf16)(v.y * inv);
  ob.z = (bf16)(v.z * inv);  ob.w = (bf16)(v.w * inv);
  *(bf16x4*)(znA + (size_t)row * DDIM + lane * 4) = oa;
  *(bf16x4*)(znB + (size_t)row * DDIM + lane * 4) = ob;
  if (lane == 0) rowsum[row] = 0.0f;
  if (blockIdx.x == 0 && threadIdx.x == 0) out[0] = 0.0f;
}

// ---------------- k2: symmetric Gram row-sums of exp ----------------
// 256 threads = 4 waves, each wave owns 32 rows of group I (A in regs).
// 2 iters of BN=64 cols of group J staged in LDS (double-buffered).
__global__ __launch_bounds__(256, 2) void k_gram(const bf16* __restrict__ znA,
                                                 const bf16* __restrict__ znB,
                                                 float* __restrict__ rowsum) {
  __shared__ __align__(16) unsigned char lds[2][BN * LDSB];
  __shared__ float colsum[GT];
  const int tid  = threadIdx.x;
  const int wave = tid >> 6, lane = tid & 63;
  const int quad = lane >> 4, l15 = lane & 15;

  // blockIdx -> unordered pair (I, J), I <= J
  int p = blockIdx.x, I = 0;
  while (p >= NTILES - I) { p -= NTILES - I; ++I; }
  const int J = I + p;
  const bool diag = (I == J);
  const int c0 = J * GT;

  if (tid < GT) colsum[tid] = 0.0f;

  // A fragments: rows I*128 + wave*32 + s*16 + l15; K=256 -> 8 k-chunks of 32.
  bf16x8 a[2][8];
#pragma unroll
  for (int s = 0; s < 2; ++s) {
    const int row = I * GT + wave * 32 + s * 16 + l15;
    const bf16x8* ap = (const bf16x8*)(znA + (size_t)row * DDIM);
#pragma unroll
    for (int k = 0; k < 8; ++k) a[s][k] = ap[k * 4 + quad];  // elems k*32 + quad*8
  }

  // staging: 256 threads x 8 chunks of 16B = 64 rows x 512B
  const int tr = tid >> 2, tc = tid & 3;
  uint4 g[8];
  {
    const unsigned char* gp = (const unsigned char*)(znB + (size_t)(c0 + tr) * DDIM);
#pragma unroll
    for (int j = 0; j < 8; ++j) g[j] = *(const uint4*)(gp + (tc + 4 * j) * 16);
  }
#pragma unroll
  for (int j = 0; j < 8; ++j)
    *(uint4*)(&lds[0][tr * LDSB + (tc + 4 * j) * 16]) = g[j];

  float sum[2][4] = {{0.f, 0.f, 0.f, 0.f}, {0.f, 0.f, 0.f, 0.f}};
  const f32x4 zero4 = {0.f, 0.f, 0.f, 0.f};

#pragma unroll
  for (int it = 0; it < 2; ++it) {
    __syncthreads();
    if (it == 0) {  // prefetch second buffer
      const unsigned char* gp = (const unsigned char*)(znB + (size_t)(c0 + BN + tr) * DDIM);
#pragma unroll
      for (int j = 0; j < 8; ++j) g[j] = *(const uint4*)(gp + (tc + 4 * j) * 16);
    }

    f32x4 acc[2][4];
#pragma unroll
    for (int s = 0; s < 2; ++s)
#pragma unroll
      for (int cs = 0; cs < 4; ++cs) acc[s][cs] = zero4;

#pragma unroll
    for (int k = 0; k < 8; ++k) {
      bf16x8 b[4];
#pragma unroll
      for (int cs = 0; cs < 4; ++cs)
        b[cs] = *(const bf16x8*)(&lds[it][(cs * 16 + l15) * LDSB + k * 64 + quad * 16]);
#pragma unroll
      for (int s = 0; s < 2; ++s)
#pragma unroll
        for (int cs = 0; cs < 4; ++cs)
          acc[s][cs] = __builtin_amdgcn_mfma_f32_16x16x32_bf16(a[s][k], b[cs], acc[s][cs], 0, 0, 0);
    }

    if (it == 0) {
#pragma unroll
      for (int j = 0; j < 8; ++j)
        *(uint4*)(&lds[1][tr * LDSB + (tc + 4 * j) * 16]) = g[j];
    }

    // epilogue: MFMA output IS the exp2 exponent (scale folded into znA)
#pragma unroll
    for (int cs = 0; cs < 4; ++cs) {
      float cp = 0.0f;
#pragma unroll
      for (int s = 0; s < 2; ++s)
#pragma unroll
        for (int r = 0; r < 4; ++r) {
          const float v = __builtin_amdgcn_exp2f(acc[s][cs][r]);
          sum[s][r] += v;  // row-side running sum (row = quad*4+r fixed per lane)
          cp += v;
        }
      if (!diag) {  // col-side: sum over 32 wave-rows -> reduce over quads
        cp += __shfl_xor(cp, 16);
        cp += __shfl_xor(cp, 32);
        if (lane < 16) atomicAdd(&colsum[it * BN + cs * 16 + l15], cp);
      }
    }
  }

  // row flush: reduce cols over l15 (C layout: col = l15, row = quad*4+r)
#pragma unroll
  for (int s = 0; s < 2; ++s)
#pragma unroll
    for (int r = 0; r < 4; ++r) {
      float v = sum[s][r];
      v += __shfl_xor(v, 1); v += __shfl_xor(v, 2);
      v += __shfl_xor(v, 4); v += __shfl_xor(v, 8);
      if (l15 == 0)
        atomicAdd(&rowsum[I * GT + wave * 32 + s * 16 + quad * 4 + r], v);
    }

  // col flush
  __syncthreads();
  if (!diag && tid < GT) atomicAdd(&rowsum[c0 + tid], colsum[tid]);
}

// ---------------- k3: finalize (pairs) ----------------
__device__ __forceinline__ float dot4(bf16x4 a, bf16x4 b) {
  return (float)a.x * (float)b.x + (float)a.y * (float)b.y +
         (float)a.z * (float)b.z + (float)a.w * (float)b.w;
}

__global__ void k_finalize(const bf16* __restrict__ znA, const bf16* __restrict__ znB,
                           const float* __restrict__ rowsum, float* __restrict__ out) {
  const int wave = threadIdx.x >> 6, lane = threadIdx.x & 63;
  const int gw = blockIdx.x * 4 + wave;  // 0..255, each handles 16 pairs
  float acc = 0.0f;
  for (int t = 0; t < 16; ++t) {
    const int q = gw * 16 + t, pq = q + NHALF;
    bf16x4 aq = *(const bf16x4*)(znA + (size_t)q  * DDIM + lane * 4);
    bf16x4 bq = *(const bf16x4*)(znB + (size_t)q  * DDIM + lane * 4);
    bf16x4 ap = *(const bf16x4*)(znA + (size_t)pq * DDIM + lane * 4);
    bf16x4 bp = *(const bf16x4*)(znB + (size_t)pq * DDIM + lane * 4);
    float dqq = dot4(aq, bq);   // exp2 exponent of GEMM diagonal, row q
    float dpp = dot4(ap, bp);   // row pq
    float dqp = dot4(aq, bp);   // = 2*log2e*cos(q,pq); sim_pair = dqp*ln2
#pragma unroll
    for (int off = 1; off < 64; off <<= 1) {
      dqq += __shfl_xor(dqq, off);
      dpp += __shfl_xor(dpp, off);
      dqp += __shfl_xor(dqp, off);
    }
    if (lane == 0) {
      const float lseq = __builtin_amdgcn_logf(rowsum[q]  - __builtin_amdgcn_exp2f(dqq)) * kLn2;
      const float lsep = __builtin_amdgcn_logf(rowsum[pq] - __builtin_amdgcn_exp2f(dpp)) * kLn2;
      acc += lseq + lsep - 2.0f * dqp * kLn2;
    }
  }
  __shared__ float ws4[4];
  if (lane == 0) ws4[wave] = acc;
  __syncthreads();
  if (threadIdx.x == 0)
    atomicAdd(out, (ws4[0] + ws4[1] + ws4[2] + ws4[3]) * (1.0f / (float)NROWS));
}

extern "C" void kernel_launch(void* const* d_in, const int* in_sizes, int n_in,
                              void* d_out, int out_size, void* d_ws, size_t ws_size,
                              hipStream_t stream) {
  const float* z1 = (const float*)d_in[0];
  const float* z2 = (const float*)d_in[1];
  unsigned char* ws = (unsigned char*)d_ws;

  // ws: znA bf16[8192*256] | znB bf16[8192*256] | rowsum f32[8192]
  bf16* znA = (bf16*)ws;
  bf16* znB = (bf16*)(ws + (size_t)NROWS * DDIM * sizeof(bf16));
  float* rowsum = (float*)(ws + 2 * (size_t)NROWS * DDIM * sizeof(bf16));
  float* out = (float*)d_out;

  hipLaunchKernelGGL(k_normalize, dim3(NROWS / 4), dim3(256), 0, stream, z1, z2, znA, znB, rowsum, out);
  hipLaunchKernelGGL(k_gram, dim3(NBLK), dim3(256), 0, stream, znA, znB, rowsum);
  hipLaunchKernelGGL(k_finalize, dim3(64), dim3(256), 0, stream, znA, znB, rowsum, out);
}